// Round 1
// baseline (788.067 us; speedup 1.0000x reference)
//
#include <hip/hip_runtime.h>
#include <math.h>

#define NN 50000
#define EE 800000
#define DD 128
#define HH 4
#define CC 32
#define LL 2
#define TOT (EE + NN)
#define NG (TOT / 16)

typedef __attribute__((ext_vector_type(8))) short short8;
typedef __attribute__((ext_vector_type(4))) short short4v;
typedef __attribute__((ext_vector_type(4))) float f32x4;
typedef __attribute__((ext_vector_type(4))) unsigned short ushort4v;

__device__ inline short bf16c(float f){
    unsigned u = __float_as_uint(f);
    u = (u + 0x7fffu + ((u >> 16) & 1u)) >> 16;
    return (short)u;
}
__device__ inline float bf2f(unsigned short h){
    return __uint_as_float(((unsigned)h) << 16);
}

// ---------------- edge sorting (by dst) ----------------

__global__ __launch_bounds__(256) void k_hist(const int* __restrict__ dstA, int* __restrict__ deg){
    int e = blockIdx.x * 256 + threadIdx.x;
    if (e < EE) atomicAdd(&deg[dstA[e]], 1);
}

__global__ __launch_bounds__(1024) void k_scan1(const int* __restrict__ deg, int* __restrict__ offs,
                                                int* __restrict__ bsum){
    __shared__ int buf[1024];
    int t = threadIdx.x;
    int i = blockIdx.x * 1024 + t;
    int v = (i < NN) ? deg[i] : 0;
    buf[t] = v;
    __syncthreads();
    for (int off = 1; off < 1024; off <<= 1){
        int x = (t >= off) ? buf[t - off] : 0;
        __syncthreads();
        buf[t] += x;
        __syncthreads();
    }
    if (i < NN) offs[i + 1] = buf[t];
    if (t == 1023) bsum[blockIdx.x] = buf[1023];
    if (i == 0) offs[0] = 0;
}

__global__ void k_scan2(int* __restrict__ bsum, int nb){
    if (threadIdx.x == 0){
        int s = 0;
        for (int b = 0; b < nb; b++){ int v = bsum[b]; bsum[b] = s; s += v; }
    }
}

__global__ __launch_bounds__(1024) void k_scan3(int* __restrict__ offs, const int* __restrict__ bsum){
    int i = blockIdx.x * 1024 + threadIdx.x;
    if (i < NN) offs[i + 1] += bsum[i >> 10];
}

// scatter: sort edges by dst; also permute+convert edge_attr rows to bf16 in sorted order
__global__ __launch_bounds__(256) void k_scatter(const int* __restrict__ srcA, const int* __restrict__ dstA,
                                                 const float* __restrict__ ea,
                                                 const int* __restrict__ offs, int* __restrict__ cnt,
                                                 int* __restrict__ srcs2, int* __restrict__ dsts2,
                                                 short* __restrict__ ea2s){
    int e = blockIdx.x * 256 + threadIdx.x;
    if (e < EE){
        int d = dstA[e];
        int pos = offs[d] + atomicAdd(&cnt[d], 1);
        srcs2[pos] = srcA[e];
        dsts2[pos] = d;
        const float* r = ea + (size_t)e * 32;
        short* o = ea2s + (size_t)pos * 32;
        #pragma unroll
        for (int qd = 0; qd < 8; qd++){
            f32x4 v = *(const f32x4*)(r + qd * 4);
            short4v h = {bf16c(v[0]), bf16c(v[1]), bf16c(v[2]), bf16c(v[3])};
            *(short4v*)(o + qd * 4) = h;
        }
    }
}

__global__ __launch_bounds__(256) void k_fill(int* __restrict__ srcs2, int* __restrict__ dsts2){
    int i = blockIdx.x * 256 + threadIdx.x;
    if (i < NN){ srcs2[EE + i] = i; dsts2[EE + i] = i; }
}

// loop_attr rows (appended at ea2s[EE..TOT)): mean of incoming sorted rows, bf16.
__global__ __launch_bounds__(256) void k_loopattr(short* __restrict__ ea2s, const int* __restrict__ offs){
    int tid = blockIdx.x * 256 + threadIdx.x;
    if (tid >= NN * CC) return;
    int n = tid >> 5, c = tid & 31;
    int b = offs[n], e = offs[n + 1];
    float s = 0.f;
    for (int p = b; p < e; ++p) s += bf2f((unsigned short)ea2s[(size_t)p * 32 + c]);
    ea2s[(size_t)(EE + n) * 32 + c] = bf16c(s / fmaxf((float)(e - b), 1.0f));
}

// ---------------- weight prep ----------------
// wt: Wt[c][k] = bf16(W[k][c]) for the 8 DxD matrices (Wl0,Wl1,Wr0,Wr1,w10,w11,w20,w21)

__global__ __launch_bounds__(256) void k_prepw(const float* __restrict__ Wl, const float* __restrict__ Wr,
                                               const float* __restrict__ w1, const float* __restrict__ w2,
                                               short* __restrict__ wt){
    int gid = blockIdx.x * 256 + threadIdx.x;      // 8 * 16384
    int mi = gid >> 14;
    int flat = gid & 16383;
    const float* base = (mi < 2) ? Wl : (mi < 4) ? Wr : (mi < 6) ? w1 : w2;
    const float* src = base + (size_t)(mi & 1) * 16384;
    int k = flat >> 7, c = flat & 127;
    wt[(size_t)mi * 16384 + c * 128 + k] = bf16c(src[flat]);
}

// weA: k_score A-fragments, laid out so af[t] = 16B vector load per lane.
// weA[((l*8 + t)*64 + lane)*8 + j] = bf16(We[l][k=q*8+j][d=t*16+m]), q=lane>>4, m=lane&15

__global__ __launch_bounds__(256) void k_prepwe(const float* __restrict__ We, short* __restrict__ weA){
    int gid = blockIdx.x * 256 + threadIdx.x;      // LL*8*64*8 = 8192
    if (gid >= LL * 4096) return;
    int j = gid & 7;
    int lane = (gid >> 3) & 63;
    int t = (gid >> 9) & 7;
    int l = gid >> 12;
    int q = lane >> 4, m = lane & 15;
    weA[gid] = bf16c(We[(size_t)l * 4096 + (q * 8 + j) * 128 + t * 16 + m]);
}

// nodes fp32 -> bf16
__global__ __launch_bounds__(256) void k_prepx(const float* __restrict__ x, short* __restrict__ xb){
    int i = blockIdx.x * 256 + threadIdx.x;        // over NN*DD/4
    if (i >= NN * DD / 4) return;
    f32x4 v = *(const f32x4*)(x + (size_t)i * 4);
    short4v h = {bf16c(v[0]), bf16c(v[1]), bf16c(v[2]), bf16c(v[3])};
    *(short4v*)(xb + (size_t)i * 4) = h;
}

// ---------------- MFMA GEMM: C[r][c] = act( sum_k X[r][k] W[k][c] + bias[c] ) ----------------
// mode bit 1: write f32 natural; bit 2: write bf16; bit 4: bf16 write uses the
// permuted "score gather" row layout: channel c -> ushort offset
//   (c>>5)*32 + ((c>>2)&3)*8 + ((c>>4)&1)*4 + (c&3)
// so that k_score lanes read 16B contiguous chunks and 4 q-lanes cover one 64B segment.

__global__ __launch_bounds__(256) void k_mg(const short* __restrict__ Xb, const short* __restrict__ Wt,
                                            const float* __restrict__ bv, float* __restrict__ Yf,
                                            unsigned short* __restrict__ Yb, int act, int mode){
    int lane = threadIdx.x & 63;
    int wave = threadIdx.x >> 6;
    int q = lane >> 4;
    int m = lane & 15;
    int cw0 = wave * 32;
    int r0 = blockIdx.x * 64;

    short8 af[2][4];
    #pragma unroll
    for (int ct = 0; ct < 2; ct++)
        #pragma unroll
        for (int ks = 0; ks < 4; ks++)
            af[ct][ks] = *(const short8*)(Wt + (size_t)(cw0 + ct * 16 + m) * 128 + ks * 32 + q * 8);

    f32x4 bq[2];
    #pragma unroll
    for (int ct = 0; ct < 2; ct++)
        bq[ct] = *(const f32x4*)(bv + cw0 + ct * 16 + q * 4);

    #pragma unroll
    for (int rt = 0; rt < 4; rt++){
        int r = r0 + rt * 16 + m;
        int rc = (r < NN) ? r : NN - 1;
        short8 bf[4];
        #pragma unroll
        for (int ks = 0; ks < 4; ks++)
            bf[ks] = *(const short8*)(Xb + (size_t)rc * 128 + ks * 32 + q * 8);

        f32x4 ac0 = {0.f, 0.f, 0.f, 0.f};
        f32x4 ac1 = {0.f, 0.f, 0.f, 0.f};
        #pragma unroll
        for (int ks = 0; ks < 4; ks++){
            ac0 = __builtin_amdgcn_mfma_f32_16x16x32_bf16(af[0][ks], bf[ks], ac0, 0, 0, 0);
            ac1 = __builtin_amdgcn_mfma_f32_16x16x32_bf16(af[1][ks], bf[ks], ac1, 0, 0, 0);
        }
        int rr = r0 + rt * 16 + m;
        if (rr < NN){
            #pragma unroll
            for (int ct = 0; ct < 2; ct++){
                f32x4 a = ct ? ac1 : ac0;
                f32x4 v;
                #pragma unroll
                for (int j = 0; j < 4; j++){
                    float x = a[j] + bq[ct][j];
                    if (act) x = fmaxf(x, 0.f);
                    v[j] = x;
                }
                int c0 = cw0 + ct * 16 + q * 4;
                if (mode & 1)
                    *(f32x4*)(Yf + (size_t)rr * 128 + c0) = v;
                if (mode & 2){
                    short4v h = {bf16c(v[0]), bf16c(v[1]), bf16c(v[2]), bf16c(v[3])};
                    int oo = (mode & 4) ? (((c0 >> 5) << 5) + (q << 3) + (((c0 >> 4) & 1) << 2))
                                        : c0;
                    *(short4v*)(Yb + (size_t)rr * 128 + oo) = h;
                }
            }
        }
    }
}

// ---------------- fused edge-score kernel: 2 MFMA tiles per iteration ----------------
// alpha[pos][h] = sum_c att[h,c] * leaky(xl[src][c] + xr[dst][c] + (ea2s[pos]@We)[c])
// xlb/xrb are in the permuted layout (see k_mg). Persistent grid, index prefetch.

__global__ __launch_bounds__(256, 4) void k_score(const short* __restrict__ ea2s,
                                               const int* __restrict__ srcs2, const int* __restrict__ dsts2,
                                               const unsigned short* __restrict__ xlb,
                                               const unsigned short* __restrict__ xrb,
                                               const short* __restrict__ weA, const float* __restrict__ att,
                                               float* __restrict__ alpha){
    int lane = threadIdx.x & 63;
    int q = lane >> 4;
    int m = lane & 15;

    short8 af[8];
    #pragma unroll
    for (int t = 0; t < 8; t++)
        af[t] = *(const short8*)(weA + ((size_t)t * 64 + lane) * 8);

    int wid = (blockIdx.x * 256 + threadIdx.x) >> 6;
    int nw = (gridDim.x * 256) >> 6;
    int g = wid * 2;
    if (g >= NG) return;

    // first iteration's indices
    int sA = srcs2[g * 16 + m], dA = dsts2[g * 16 + m];
    int pB0 = ((g + 1) < NG) ? (g + 1) * 16 + m : g * 16 + m;
    int sB = srcs2[pB0], dB = dsts2[pB0];

    while (g < NG){
        bool hB = (g + 1) < NG;
        int posA = g * 16 + m;
        int posB = hB ? posA + 16 : posA;

        // gathers: 16B/lane, 4 q-lanes contiguous per row (permuted layout)
        const unsigned short* pxA = xlb + (size_t)sA * 128 + q * 8;
        const unsigned short* prA = xrb + (size_t)dA * 128 + q * 8;
        const unsigned short* pxB = xlb + (size_t)sB * 128 + q * 8;
        const unsigned short* prB = xrb + (size_t)dB * 128 + q * 8;
        short8 gxA[4], grA[4], gxB[4], grB[4];
        #pragma unroll
        for (int u = 0; u < 4; u++){
            gxA[u] = *(const short8*)(pxA + u * 32);
            grA[u] = *(const short8*)(prA + u * 32);
            gxB[u] = *(const short8*)(pxB + u * 32);
            grB[u] = *(const short8*)(prB + u * 32);
        }
        short8 bfA = __builtin_nontemporal_load((const short8*)(ea2s + (size_t)posA * 32 + q * 8));
        short8 bfB = __builtin_nontemporal_load((const short8*)(ea2s + (size_t)posB * 32 + q * 8));

        // prefetch next iteration's indices so the idx->gather chain overlaps compute
        int gn = g + nw * 2;
        int sA2 = sA, dA2 = dA, sB2 = sB, dB2 = dB;
        if (gn < NG){
            sA2 = srcs2[gn * 16 + m]; dA2 = dsts2[gn * 16 + m];
            int pB = ((gn + 1) < NG) ? (gn + 1) * 16 + m : gn * 16 + m;
            sB2 = srcs2[pB]; dB2 = dsts2[pB];
        }

        float psA[4] = {0.f,0.f,0.f,0.f}, psB[4] = {0.f,0.f,0.f,0.f};
        #pragma unroll
        for (int t = 0; t < 8; t++){
            f32x4 z = {0.f,0.f,0.f,0.f};
            f32x4 cA = __builtin_amdgcn_mfma_f32_16x16x32_bf16(af[t], bfA, z, 0, 0, 0);
            f32x4 cB = __builtin_amdgcn_mfma_f32_16x16x32_bf16(af[t], bfB, z, 0, 0, 0);
            f32x4 av = *(const f32x4*)(att + t * 16 + q * 4);
            int u = t >> 1, lo = (t & 1) * 4;
            #pragma unroll
            for (int r = 0; r < 4; r++){
                float ma = cA[r] + bf2f((unsigned short)gxA[u][lo + r]) + bf2f((unsigned short)grA[u][lo + r]);
                float mb = cB[r] + bf2f((unsigned short)gxB[u][lo + r]) + bf2f((unsigned short)grB[u][lo + r]);
                ma = (ma > 0.f) ? ma : 0.2f * ma;
                mb = (mb > 0.f) ? mb : 0.2f * mb;
                psA[t >> 1] = fmaf(av[r], ma, psA[t >> 1]);
                psB[t >> 1] = fmaf(av[r], mb, psB[t >> 1]);
            }
        }
        #pragma unroll
        for (int h = 0; h < 4; h++){
            psA[h] += __shfl_xor(psA[h], 16);
            psA[h] += __shfl_xor(psA[h], 32);
            psB[h] += __shfl_xor(psB[h], 16);
            psB[h] += __shfl_xor(psB[h], 32);
        }
        if (lane < 16){
            f32x4 oA = {psA[0], psA[1], psA[2], psA[3]};
            *(f32x4*)(alpha + (size_t)posA * 4) = oA;
            if (hB){
                f32x4 oB = {psB[0], psB[1], psB[2], psB[3]};
                *(f32x4*)(alpha + (size_t)posB * 4) = oB;
            }
        }
        g = gn; sA = sA2; dA = dA2; sB = sB2; dB = dB2;
    }
}

// ---------------- GATv2 softmax + aggregation (bf16 gathers, 2 adjacent ch/lane) ----------------
// lane owns channels {2*lane, 2*lane+1}; both in head h = lane>>4 -> single softmax state.
// xlb is in the permuted layout; per-lane ushort offset computed from channel.

__global__ __launch_bounds__(256) void k_gat2(const unsigned short* __restrict__ xlb,
                                              const int* __restrict__ srcs2, const int* __restrict__ offs,
                                              const float* __restrict__ alpha, const float* __restrict__ bias,
                                              unsigned short* __restrict__ out){
    int n = blockIdx.x * 4 + (threadIdx.x >> 6);
    int lane = threadIdx.x & 63;
    int c0 = lane * 2;
    int h = lane >> 4;
    // permuted ushort offset of channels {c0, c0+1} (adjacent in permuted layout since c0 even)
    int po = ((c0 >> 5) << 5) + (((c0 >> 2) & 3) << 3) + (((c0 >> 4) & 1) << 2) + (c0 & 3);

    int beg = offs[n];
    int deg = offs[n + 1] - beg;
    int cnt = deg + 1;   // + self-loop (position EE+n)

    float M = -INFINITY, S = 0.f, A0 = 0.f, A1 = 0.f;

    for (int i = 0; i < cnt; i += 4){
        float a[4]; unsigned x[4];
        #pragma unroll
        for (int u = 0; u < 4; u++){
            int iu = i + u;
            int p = (iu < deg) ? beg + iu : EE + n;
            int s = srcs2[p];
            a[u] = alpha[(size_t)p * 4 + h];
            x[u] = *(const unsigned*)(xlb + (size_t)s * 128 + po);
            if (iu >= cnt) a[u] = -INFINITY;
        }
        float nM = fmaxf(fmaxf(fmaxf(a[0], a[1]), fmaxf(a[2], a[3])), M);
        float rs = __expf(M - nM);
        float w0 = __expf(a[0] - nM);
        float w1 = __expf(a[1] - nM);
        float w2 = __expf(a[2] - nM);
        float w3 = __expf(a[3] - nM);
        S = S * rs + w0 + w1 + w2 + w3;
        A0 = A0 * rs + w0 * bf2f((unsigned short)(x[0] & 0xffffu))
                     + w1 * bf2f((unsigned short)(x[1] & 0xffffu))
                     + w2 * bf2f((unsigned short)(x[2] & 0xffffu))
                     + w3 * bf2f((unsigned short)(x[3] & 0xffffu));
        A1 = A1 * rs + w0 * bf2f((unsigned short)(x[0] >> 16))
                     + w1 * bf2f((unsigned short)(x[1] >> 16))
                     + w2 * bf2f((unsigned short)(x[2] >> 16))
                     + w3 * bf2f((unsigned short)(x[3] >> 16));
        M = nM;
    }
    float inv = 1.f / (S + 1e-16f);
    float v0 = A0 * inv + bias[c0];
    float v1 = A1 * inv + bias[c0 + 1];
    unsigned o = ((unsigned)(unsigned short)bf16c(v0)) | (((unsigned)(unsigned short)bf16c(v1)) << 16);
    *(unsigned*)(out + (size_t)n * 128 + c0) = o;
}

// ---------------- driver ----------------

extern "C" void kernel_launch(void* const* d_in, const int* in_sizes, int n_in,
                              void* d_out, int out_size, void* d_ws, size_t ws_size,
                              hipStream_t stream){
    const float* nodes = (const float*)d_in[0];
    const int*   ei    = (const int*)d_in[1];
    const float* ea    = (const float*)d_in[2];
    const float* Wl    = (const float*)d_in[3];
    const float* bl    = (const float*)d_in[4];
    const float* Wr    = (const float*)d_in[5];
    const float* br    = (const float*)d_in[6];
    const float* We    = (const float*)d_in[7];
    const float* att   = (const float*)d_in[8];
    const float* bias  = (const float*)d_in[9];
    const float* w1    = (const float*)d_in[10];
    const float* b1    = (const float*)d_in[11];
    const float* w2    = (const float*)d_in[12];
    const float* b2    = (const float*)d_in[13];
    const int* srcA = ei;
    const int* dstA = ei + EE;

    char* ws = (char*)d_ws;
    size_t off = 0;
    auto alloc = [&](size_t bytes) -> char* {
        off = (off + 255) & ~(size_t)255;
        char* p = ws + off;
        off += bytes;
        return p;
    };
    int*   deg   = (int*)alloc(NN * 4);
    int*   cnt   = (int*)alloc(NN * 4);
    int*   offs  = (int*)alloc((NN + 1) * 4);
    int*   bsum  = (int*)alloc(64 * 4);
    int*   srcs2 = (int*)alloc((size_t)TOT * 4);
    int*   dsts2 = (int*)alloc((size_t)TOT * 4);
    short* ea2s  = (short*)alloc((size_t)TOT * CC * 2);
    float* alpha = (float*)alloc((size_t)TOT * 4 * 4);
    short* wt    = (short*)alloc((size_t)8 * 16384 * 2);          // 8 transposed bf16 weights
    short* weA   = (short*)alloc((size_t)LL * 4096 * 2);          // k_score A-frag table
    short* xb    = (short*)alloc((size_t)NN * DD * 2);            // current x, bf16
    unsigned short* xlb = (unsigned short*)alloc((size_t)NN * DD * 2);
    unsigned short* xrb = (unsigned short*)alloc((size_t)NN * DD * 2);
    unsigned short* bgb = (unsigned short*)alloc((size_t)NN * DD * 2);  // gat2 out, bf16
    unsigned short* bhb = (unsigned short*)alloc((size_t)NN * DD * 2);  // MLP hidden, bf16
    unsigned short* bxb = (unsigned short*)alloc((size_t)NN * DD * 2);  // inter-layer x, bf16

    hipMemsetAsync(deg, 0, NN * 4, stream);
    hipMemsetAsync(cnt, 0, NN * 4, stream);
    k_hist<<<(EE + 255) / 256, 256, 0, stream>>>(dstA, deg);
    int nb = (NN + 1023) / 1024;
    k_scan1<<<nb, 1024, 0, stream>>>(deg, offs, bsum);
    k_scan2<<<1, 64, 0, stream>>>(bsum, nb);
    k_scan3<<<nb, 1024, 0, stream>>>(offs, bsum);
    k_scatter<<<(EE + 255) / 256, 256, 0, stream>>>(srcA, dstA, ea, offs, cnt, srcs2, dsts2, ea2s);
    k_fill<<<(NN + 255) / 256, 256, 0, stream>>>(srcs2, dsts2);
    k_loopattr<<<(NN * CC + 255) / 256, 256, 0, stream>>>(ea2s, offs);
    k_prepw<<<8 * 16384 / 256, 256, 0, stream>>>(Wl, Wr, w1, w2, wt);
    k_prepwe<<<(LL * 4096 + 255) / 256, 256, 0, stream>>>(We, weA);
    k_prepx<<<(NN * DD / 4 + 255) / 256, 256, 0, stream>>>(nodes, xb);

    const int GB = (NN + 63) / 64;   // 782
    short* wtWl = wt;
    short* wtWr = wt + 2 * 16384;
    short* wtw1 = wt + 4 * 16384;
    short* wtw2 = wt + 6 * 16384;

    const short* x = xb;
    for (int l = 0; l < LL; l++){
        // xl/xr projections written in the permuted score-gather layout (mode 2|4)
        k_mg<<<GB, 256, 0, stream>>>(x, wtWl + l * 16384, bl + l * DD, nullptr, xlb, 0, 6);
        k_mg<<<GB, 256, 0, stream>>>(x, wtWr + l * 16384, br + l * DD, nullptr, xrb, 0, 6);
        k_score<<<1024, 256, 0, stream>>>(ea2s, srcs2, dsts2, xlb, xrb,
                                          weA + l * 4096, att + l * HH * CC, alpha);
        k_gat2<<<NN / 4, 256, 0, stream>>>(xlb, srcs2, offs, alpha, bias + l * DD, bgb);
        k_mg<<<GB, 256, 0, stream>>>((const short*)bgb, wtw1 + l * 16384, b1 + l * DD, nullptr, bhb, 1, 2);
        if (l == LL - 1)
            k_mg<<<GB, 256, 0, stream>>>((const short*)bhb, wtw2 + l * 16384, b2 + l * DD,
                                         (float*)d_out, nullptr, 0, 1);
        else
            k_mg<<<GB, 256, 0, stream>>>((const short*)bhb, wtw2 + l * 16384, b2 + l * DD,
                                         nullptr, bxb, 0, 2);
        x = (const short*)bxb;
    }
}

// Round 2
// 649.774 us; speedup vs baseline: 1.2128x; 1.2128x over previous
//
#include <hip/hip_runtime.h>
#include <math.h>

#define NN 50000
#define EE 800000
#define DD 128
#define HH 4
#define CC 32
#define LL 2
#define TOT (EE + NN)
#define NG (TOT / 16)

typedef __attribute__((ext_vector_type(8))) short short8;
typedef __attribute__((ext_vector_type(4))) short short4v;
typedef __attribute__((ext_vector_type(4))) float f32x4;
typedef __attribute__((ext_vector_type(4))) unsigned short ushort4v;

__device__ inline short bf16c(float f){
    unsigned u = __float_as_uint(f);
    u = (u + 0x7fffu + ((u >> 16) & 1u)) >> 16;
    return (short)u;
}
__device__ inline float bf2f(unsigned short h){
    return __uint_as_float(((unsigned)h) << 16);
}

// ---------------- edge sorting (by dst) ----------------

__global__ __launch_bounds__(256) void k_hist(const int* __restrict__ dstA, int* __restrict__ deg){
    int e = blockIdx.x * 256 + threadIdx.x;
    if (e < EE) atomicAdd(&deg[dstA[e]], 1);
}

__global__ __launch_bounds__(1024) void k_scan1(const int* __restrict__ deg, int* __restrict__ offs,
                                                int* __restrict__ bsum){
    __shared__ int buf[1024];
    int t = threadIdx.x;
    int i = blockIdx.x * 1024 + t;
    int v = (i < NN) ? deg[i] : 0;
    buf[t] = v;
    __syncthreads();
    for (int off = 1; off < 1024; off <<= 1){
        int x = (t >= off) ? buf[t - off] : 0;
        __syncthreads();
        buf[t] += x;
        __syncthreads();
    }
    if (i < NN) offs[i + 1] = buf[t];
    if (t == 1023) bsum[blockIdx.x] = buf[1023];
    if (i == 0) offs[0] = 0;
}

__global__ void k_scan2(int* __restrict__ bsum, int nb){
    if (threadIdx.x == 0){
        int s = 0;
        for (int b = 0; b < nb; b++){ int v = bsum[b]; bsum[b] = s; s += v; }
    }
}

__global__ __launch_bounds__(1024) void k_scan3(int* __restrict__ offs, const int* __restrict__ bsum){
    int i = blockIdx.x * 1024 + threadIdx.x;
    if (i < NN) offs[i + 1] += bsum[i >> 10];
}

// scatter: sort edges by dst; also permute+convert edge_attr rows to bf16 in sorted order
__global__ __launch_bounds__(256) void k_scatter(const int* __restrict__ srcA, const int* __restrict__ dstA,
                                                 const float* __restrict__ ea,
                                                 const int* __restrict__ offs, int* __restrict__ cnt,
                                                 int* __restrict__ srcs2, int* __restrict__ dsts2,
                                                 short* __restrict__ ea2s){
    int e = blockIdx.x * 256 + threadIdx.x;
    if (e < EE){
        int d = dstA[e];
        int pos = offs[d] + atomicAdd(&cnt[d], 1);
        srcs2[pos] = srcA[e];
        dsts2[pos] = d;
        const float* r = ea + (size_t)e * 32;
        short* o = ea2s + (size_t)pos * 32;
        #pragma unroll
        for (int qd = 0; qd < 8; qd++){
            f32x4 v = *(const f32x4*)(r + qd * 4);
            short4v h = {bf16c(v[0]), bf16c(v[1]), bf16c(v[2]), bf16c(v[3])};
            *(short4v*)(o + qd * 4) = h;
        }
    }
}

__global__ __launch_bounds__(256) void k_fill(int* __restrict__ srcs2, int* __restrict__ dsts2){
    int i = blockIdx.x * 256 + threadIdx.x;
    if (i < NN){ srcs2[EE + i] = i; dsts2[EE + i] = i; }
}

// loop_attr rows (appended at ea2s[EE..TOT)): mean of incoming sorted rows, bf16.
__global__ __launch_bounds__(256) void k_loopattr(short* __restrict__ ea2s, const int* __restrict__ offs){
    int tid = blockIdx.x * 256 + threadIdx.x;
    if (tid >= NN * CC) return;
    int n = tid >> 5, c = tid & 31;
    int b = offs[n], e = offs[n + 1];
    float s = 0.f;
    for (int p = b; p < e; ++p) s += bf2f((unsigned short)ea2s[(size_t)p * 32 + c]);
    ea2s[(size_t)(EE + n) * 32 + c] = bf16c(s / fmaxf((float)(e - b), 1.0f));
}

// ---------------- weight prep ----------------
// wt: Wt[c][k] = bf16(W[k][c]) for the 8 DxD matrices (Wl0,Wl1,Wr0,Wr1,w10,w11,w20,w21)

__global__ __launch_bounds__(256) void k_prepw(const float* __restrict__ Wl, const float* __restrict__ Wr,
                                               const float* __restrict__ w1, const float* __restrict__ w2,
                                               short* __restrict__ wt){
    int gid = blockIdx.x * 256 + threadIdx.x;      // 8 * 16384
    int mi = gid >> 14;
    int flat = gid & 16383;
    const float* base = (mi < 2) ? Wl : (mi < 4) ? Wr : (mi < 6) ? w1 : w2;
    const float* src = base + (size_t)(mi & 1) * 16384;
    int k = flat >> 7, c = flat & 127;
    wt[(size_t)mi * 16384 + c * 128 + k] = bf16c(src[flat]);
}

// weA: k_score A-fragments, laid out so af[t] = 16B vector load per lane.
// weA[((l*8 + t)*64 + lane)*8 + j] = bf16(We[l][k=q*8+j][d=t*16+m]), q=lane>>4, m=lane&15

__global__ __launch_bounds__(256) void k_prepwe(const float* __restrict__ We, short* __restrict__ weA){
    int gid = blockIdx.x * 256 + threadIdx.x;      // LL*8*64*8 = 8192
    if (gid >= LL * 4096) return;
    int j = gid & 7;
    int lane = (gid >> 3) & 63;
    int t = (gid >> 9) & 7;
    int l = gid >> 12;
    int q = lane >> 4, m = lane & 15;
    weA[gid] = bf16c(We[(size_t)l * 4096 + (q * 8 + j) * 128 + t * 16 + m]);
}

// nodes fp32 -> bf16
__global__ __launch_bounds__(256) void k_prepx(const float* __restrict__ x, short* __restrict__ xb){
    int i = blockIdx.x * 256 + threadIdx.x;        // over NN*DD/4
    if (i >= NN * DD / 4) return;
    f32x4 v = *(const f32x4*)(x + (size_t)i * 4);
    short4v h = {bf16c(v[0]), bf16c(v[1]), bf16c(v[2]), bf16c(v[3])};
    *(short4v*)(xb + (size_t)i * 4) = h;
}

// ---------------- MFMA GEMM: C[r][c] = act( sum_k X[r][k] W[k][c] + bias[c] ) ----------------
// mode bit 1: write f32 natural; bit 2: write bf16; bit 4: bf16 write uses the
// permuted "score gather" row layout: channel c -> ushort offset
//   (c>>5)*32 + ((c>>2)&3)*8 + ((c>>4)&1)*4 + (c&3)
// so that k_score lanes read 16B contiguous chunks and 4 q-lanes cover one 64B segment.

__global__ __launch_bounds__(256) void k_mg(const short* __restrict__ Xb, const short* __restrict__ Wt,
                                            const float* __restrict__ bv, float* __restrict__ Yf,
                                            unsigned short* __restrict__ Yb, int act, int mode){
    int lane = threadIdx.x & 63;
    int wave = threadIdx.x >> 6;
    int q = lane >> 4;
    int m = lane & 15;
    int cw0 = wave * 32;
    int r0 = blockIdx.x * 64;

    short8 af[2][4];
    #pragma unroll
    for (int ct = 0; ct < 2; ct++)
        #pragma unroll
        for (int ks = 0; ks < 4; ks++)
            af[ct][ks] = *(const short8*)(Wt + (size_t)(cw0 + ct * 16 + m) * 128 + ks * 32 + q * 8);

    f32x4 bq[2];
    #pragma unroll
    for (int ct = 0; ct < 2; ct++)
        bq[ct] = *(const f32x4*)(bv + cw0 + ct * 16 + q * 4);

    #pragma unroll
    for (int rt = 0; rt < 4; rt++){
        int r = r0 + rt * 16 + m;
        int rc = (r < NN) ? r : NN - 1;
        short8 bf[4];
        #pragma unroll
        for (int ks = 0; ks < 4; ks++)
            bf[ks] = *(const short8*)(Xb + (size_t)rc * 128 + ks * 32 + q * 8);

        f32x4 ac0 = {0.f, 0.f, 0.f, 0.f};
        f32x4 ac1 = {0.f, 0.f, 0.f, 0.f};
        #pragma unroll
        for (int ks = 0; ks < 4; ks++){
            ac0 = __builtin_amdgcn_mfma_f32_16x16x32_bf16(af[0][ks], bf[ks], ac0, 0, 0, 0);
            ac1 = __builtin_amdgcn_mfma_f32_16x16x32_bf16(af[1][ks], bf[ks], ac1, 0, 0, 0);
        }
        int rr = r0 + rt * 16 + m;
        if (rr < NN){
            #pragma unroll
            for (int ct = 0; ct < 2; ct++){
                f32x4 a = ct ? ac1 : ac0;
                f32x4 v;
                #pragma unroll
                for (int j = 0; j < 4; j++){
                    float x = a[j] + bq[ct][j];
                    if (act) x = fmaxf(x, 0.f);
                    v[j] = x;
                }
                int c0 = cw0 + ct * 16 + q * 4;
                if (mode & 1)
                    *(f32x4*)(Yf + (size_t)rr * 128 + c0) = v;
                if (mode & 2){
                    short4v h = {bf16c(v[0]), bf16c(v[1]), bf16c(v[2]), bf16c(v[3])};
                    int oo = (mode & 4) ? (((c0 >> 5) << 5) + (q << 3) + (((c0 >> 4) & 1) << 2))
                                        : c0;
                    *(short4v*)(Yb + (size_t)rr * 128 + oo) = h;
                }
            }
        }
    }
}

// ---------------- fused edge-score kernel: 2 MFMA tiles per wave, one-shot ----------------
// alpha[pos][h] = sum_c att[h,c] * leaky(xl[src][c] + xr[dst][c] + (ea2s[pos]@We)[c])
// xlb/xrb are in the permuted layout (see k_mg): lane reads 4x16B contiguous chunks,
// 4 q-lanes cover one 64B segment per row. NON-persistent launch: the HW dispatcher
// provides a moving window over the dst-sorted tiles (L2 locality for xrb/ea2s/alpha).

__global__ __launch_bounds__(256) void k_score(const short* __restrict__ ea2s,
                                               const int* __restrict__ srcs2, const int* __restrict__ dsts2,
                                               const unsigned short* __restrict__ xlb,
                                               const unsigned short* __restrict__ xrb,
                                               const short* __restrict__ weA, const float* __restrict__ att,
                                               float* __restrict__ alpha){
    int lane = threadIdx.x & 63;
    int q = lane >> 4;
    int m = lane & 15;

    short8 af[8];
    #pragma unroll
    for (int t = 0; t < 8; t++)
        af[t] = *(const short8*)(weA + ((size_t)t * 64 + lane) * 8);

    int wid = (blockIdx.x * 256 + threadIdx.x) >> 6;
    int g = wid * 2;
    if (g >= NG) return;

    bool hB = (g + 1) < NG;
    int posA = g * 16 + m;
    int posB = hB ? posA + 16 : posA;

    int sA = srcs2[posA], dA = dsts2[posA];
    int sB = srcs2[posB], dB = dsts2[posB];

    // gathers: 16B/lane, 4 q-lanes contiguous per row (permuted layout)
    const unsigned short* pxA = xlb + (size_t)sA * 128 + q * 8;
    const unsigned short* prA = xrb + (size_t)dA * 128 + q * 8;
    const unsigned short* pxB = xlb + (size_t)sB * 128 + q * 8;
    const unsigned short* prB = xrb + (size_t)dB * 128 + q * 8;
    short8 gxA[4], grA[4], gxB[4], grB[4];
    #pragma unroll
    for (int u = 0; u < 4; u++){
        gxA[u] = *(const short8*)(pxA + u * 32);
        grA[u] = *(const short8*)(prA + u * 32);
        gxB[u] = *(const short8*)(pxB + u * 32);
        grB[u] = *(const short8*)(prB + u * 32);
    }
    short8 bfA = __builtin_nontemporal_load((const short8*)(ea2s + (size_t)posA * 32 + q * 8));
    short8 bfB = __builtin_nontemporal_load((const short8*)(ea2s + (size_t)posB * 32 + q * 8));

    float psA[4] = {0.f,0.f,0.f,0.f}, psB[4] = {0.f,0.f,0.f,0.f};
    #pragma unroll
    for (int t = 0; t < 8; t++){
        f32x4 z = {0.f,0.f,0.f,0.f};
        f32x4 cA = __builtin_amdgcn_mfma_f32_16x16x32_bf16(af[t], bfA, z, 0, 0, 0);
        f32x4 cB = __builtin_amdgcn_mfma_f32_16x16x32_bf16(af[t], bfB, z, 0, 0, 0);
        f32x4 av = *(const f32x4*)(att + t * 16 + q * 4);
        int u = t >> 1, lo = (t & 1) * 4;
        #pragma unroll
        for (int r = 0; r < 4; r++){
            float ma = cA[r] + bf2f((unsigned short)gxA[u][lo + r]) + bf2f((unsigned short)grA[u][lo + r]);
            float mb = cB[r] + bf2f((unsigned short)gxB[u][lo + r]) + bf2f((unsigned short)grB[u][lo + r]);
            ma = (ma > 0.f) ? ma : 0.2f * ma;
            mb = (mb > 0.f) ? mb : 0.2f * mb;
            psA[t >> 1] = fmaf(av[r], ma, psA[t >> 1]);
            psB[t >> 1] = fmaf(av[r], mb, psB[t >> 1]);
        }
    }
    #pragma unroll
    for (int h = 0; h < 4; h++){
        psA[h] += __shfl_xor(psA[h], 16);
        psA[h] += __shfl_xor(psA[h], 32);
        psB[h] += __shfl_xor(psB[h], 16);
        psB[h] += __shfl_xor(psB[h], 32);
    }
    if (lane < 16){
        f32x4 oA = {psA[0], psA[1], psA[2], psA[3]};
        *(f32x4*)(alpha + (size_t)posA * 4) = oA;
        if (hB){
            f32x4 oB = {psB[0], psB[1], psB[2], psB[3]};
            *(f32x4*)(alpha + (size_t)posB * 4) = oB;
        }
    }
}

// ---------------- GATv2 softmax + aggregation (bf16 gathers, 2 adjacent ch/lane) ----------------
// lane owns channels {2*lane, 2*lane+1}; both in head h = lane>>4 -> single softmax state.
// xlb is in the permuted layout; per-lane ushort offset computed from channel.

__global__ __launch_bounds__(256) void k_gat2(const unsigned short* __restrict__ xlb,
                                              const int* __restrict__ srcs2, const int* __restrict__ offs,
                                              const float* __restrict__ alpha, const float* __restrict__ bias,
                                              unsigned short* __restrict__ out){
    int n = blockIdx.x * 4 + (threadIdx.x >> 6);
    int lane = threadIdx.x & 63;
    int c0 = lane * 2;
    int h = lane >> 4;
    // permuted ushort offset of channels {c0, c0+1} (adjacent in permuted layout since c0 even)
    int po = ((c0 >> 5) << 5) + (((c0 >> 2) & 3) << 3) + (((c0 >> 4) & 1) << 2) + (c0 & 3);

    int beg = offs[n];
    int deg = offs[n + 1] - beg;
    int cnt = deg + 1;   // + self-loop (position EE+n)

    float M = -INFINITY, S = 0.f, A0 = 0.f, A1 = 0.f;

    for (int i = 0; i < cnt; i += 4){
        float a[4]; unsigned x[4];
        #pragma unroll
        for (int u = 0; u < 4; u++){
            int iu = i + u;
            int p = (iu < deg) ? beg + iu : EE + n;
            int s = srcs2[p];
            a[u] = alpha[(size_t)p * 4 + h];
            x[u] = *(const unsigned*)(xlb + (size_t)s * 128 + po);
            if (iu >= cnt) a[u] = -INFINITY;
        }
        float nM = fmaxf(fmaxf(fmaxf(a[0], a[1]), fmaxf(a[2], a[3])), M);
        float rs = __expf(M - nM);
        float w0 = __expf(a[0] - nM);
        float w1 = __expf(a[1] - nM);
        float w2 = __expf(a[2] - nM);
        float w3 = __expf(a[3] - nM);
        S = S * rs + w0 + w1 + w2 + w3;
        A0 = A0 * rs + w0 * bf2f((unsigned short)(x[0] & 0xffffu))
                     + w1 * bf2f((unsigned short)(x[1] & 0xffffu))
                     + w2 * bf2f((unsigned short)(x[2] & 0xffffu))
                     + w3 * bf2f((unsigned short)(x[3] & 0xffffu));
        A1 = A1 * rs + w0 * bf2f((unsigned short)(x[0] >> 16))
                     + w1 * bf2f((unsigned short)(x[1] >> 16))
                     + w2 * bf2f((unsigned short)(x[2] >> 16))
                     + w3 * bf2f((unsigned short)(x[3] >> 16));
        M = nM;
    }
    float inv = 1.f / (S + 1e-16f);
    float v0 = A0 * inv + bias[c0];
    float v1 = A1 * inv + bias[c0 + 1];
    unsigned o = ((unsigned)(unsigned short)bf16c(v0)) | (((unsigned)(unsigned short)bf16c(v1)) << 16);
    *(unsigned*)(out + (size_t)n * 128 + c0) = o;
}

// ---------------- driver ----------------

extern "C" void kernel_launch(void* const* d_in, const int* in_sizes, int n_in,
                              void* d_out, int out_size, void* d_ws, size_t ws_size,
                              hipStream_t stream){
    const float* nodes = (const float*)d_in[0];
    const int*   ei    = (const int*)d_in[1];
    const float* ea    = (const float*)d_in[2];
    const float* Wl    = (const float*)d_in[3];
    const float* bl    = (const float*)d_in[4];
    const float* Wr    = (const float*)d_in[5];
    const float* br    = (const float*)d_in[6];
    const float* We    = (const float*)d_in[7];
    const float* att   = (const float*)d_in[8];
    const float* bias  = (const float*)d_in[9];
    const float* w1    = (const float*)d_in[10];
    const float* b1    = (const float*)d_in[11];
    const float* w2    = (const float*)d_in[12];
    const float* b2    = (const float*)d_in[13];
    const int* srcA = ei;
    const int* dstA = ei + EE;

    char* ws = (char*)d_ws;
    size_t off = 0;
    auto alloc = [&](size_t bytes) -> char* {
        off = (off + 255) & ~(size_t)255;
        char* p = ws + off;
        off += bytes;
        return p;
    };
    int*   deg   = (int*)alloc(NN * 4);
    int*   cnt   = (int*)alloc(NN * 4);
    int*   offs  = (int*)alloc((NN + 1) * 4);
    int*   bsum  = (int*)alloc(64 * 4);
    int*   srcs2 = (int*)alloc((size_t)TOT * 4);
    int*   dsts2 = (int*)alloc((size_t)TOT * 4);
    short* ea2s  = (short*)alloc((size_t)TOT * CC * 2);
    float* alpha = (float*)alloc((size_t)TOT * 4 * 4);
    short* wt    = (short*)alloc((size_t)8 * 16384 * 2);          // 8 transposed bf16 weights
    short* weA   = (short*)alloc((size_t)LL * 4096 * 2);          // k_score A-frag table
    short* xb    = (short*)alloc((size_t)NN * DD * 2);            // current x, bf16
    unsigned short* xlb = (unsigned short*)alloc((size_t)NN * DD * 2);
    unsigned short* xrb = (unsigned short*)alloc((size_t)NN * DD * 2);
    unsigned short* bgb = (unsigned short*)alloc((size_t)NN * DD * 2);  // gat2 out, bf16
    unsigned short* bhb = (unsigned short*)alloc((size_t)NN * DD * 2);  // MLP hidden, bf16
    unsigned short* bxb = (unsigned short*)alloc((size_t)NN * DD * 2);  // inter-layer x, bf16

    hipMemsetAsync(deg, 0, NN * 4, stream);
    hipMemsetAsync(cnt, 0, NN * 4, stream);
    k_hist<<<(EE + 255) / 256, 256, 0, stream>>>(dstA, deg);
    int nb = (NN + 1023) / 1024;
    k_scan1<<<nb, 1024, 0, stream>>>(deg, offs, bsum);
    k_scan2<<<1, 64, 0, stream>>>(bsum, nb);
    k_scan3<<<nb, 1024, 0, stream>>>(offs, bsum);
    k_scatter<<<(EE + 255) / 256, 256, 0, stream>>>(srcA, dstA, ea, offs, cnt, srcs2, dsts2, ea2s);
    k_fill<<<(NN + 255) / 256, 256, 0, stream>>>(srcs2, dsts2);
    k_loopattr<<<(NN * CC + 255) / 256, 256, 0, stream>>>(ea2s, offs);
    k_prepw<<<8 * 16384 / 256, 256, 0, stream>>>(Wl, Wr, w1, w2, wt);
    k_prepwe<<<(LL * 4096 + 255) / 256, 256, 0, stream>>>(We, weA);
    k_prepx<<<(NN * DD / 4 + 255) / 256, 256, 0, stream>>>(nodes, xb);

    const int GB = (NN + 63) / 64;   // 782
    const int SCORE_WAVES = (NG + 1) / 2;            // one wave per 2 adjacent tiles
    const int SCORE_BLOCKS = (SCORE_WAVES + 3) / 4;  // 4 waves per block
    short* wtWl = wt;
    short* wtWr = wt + 2 * 16384;
    short* wtw1 = wt + 4 * 16384;
    short* wtw2 = wt + 6 * 16384;

    const short* x = xb;
    for (int l = 0; l < LL; l++){
        // xl/xr projections written in the permuted score-gather layout (mode 2|4)
        k_mg<<<GB, 256, 0, stream>>>(x, wtWl + l * 16384, bl + l * DD, nullptr, xlb, 0, 6);
        k_mg<<<GB, 256, 0, stream>>>(x, wtWr + l * 16384, br + l * DD, nullptr, xrb, 0, 6);
        k_score<<<SCORE_BLOCKS, 256, 0, stream>>>(ea2s, srcs2, dsts2, xlb, xrb,
                                                  weA + l * 4096, att + l * HH * CC, alpha);
        k_gat2<<<NN / 4, 256, 0, stream>>>(xlb, srcs2, offs, alpha, bias + l * DD, bgb);
        k_mg<<<GB, 256, 0, stream>>>((const short*)bgb, wtw1 + l * 16384, b1 + l * DD, nullptr, bhb, 1, 2);
        if (l == LL - 1)
            k_mg<<<GB, 256, 0, stream>>>((const short*)bhb, wtw2 + l * 16384, b2 + l * DD,
                                         (float*)d_out, nullptr, 0, 1);
        else
            k_mg<<<GB, 256, 0, stream>>>((const short*)bhb, wtw2 + l * 16384, b2 + l * DD,
                                         nullptr, bxb, 0, 2);
        x = (const short*)bxb;
    }
}